// Round 2
// baseline (227.581 us; speedup 1.0000x reference)
//
#include <hip/hip_runtime.h>
#include <hip/hip_bf16.h>
#include <math.h>

// HGCN decoder, B=512, N=128, D=256, F=16, L=3, c=1 Poincare ball.
// One block per batch. sT (tangent features) wave-private-by-row in LDS across
// all 3 layers. V^T chunked over n (8 chunks of 32, double-buffered) so
// LDS = 64 + 16 = 80KB -> 2 blocks/CU. FP16 MFMA 16x16x32, f32 accumulate.
// Orientations chosen so both epilogues are ds_write_b64 (no scalar LDS).

typedef _Float16 f16;
typedef f16 f16x8 __attribute__((ext_vector_type(8)));
typedef f16 f16x4 __attribute__((ext_vector_type(4)));
typedef float f32x4 __attribute__((ext_vector_type(4)));

#define NB 512
#define NN 128
#define ND 256
#define NF 16
#define NL 3

#define EPSV   1e-7f
#define MAXN   0.99999f      // 1 - 1e-5
#define ATHMAX 6.1030340f    // atanh(1 - 1e-5)

// sT[128][256] f16 (row 512B), 16B-chunk XOR swizzle with row&7.
__device__ __forceinline__ int sT_idx(int m, int k) {
    return m * ND + ((((k >> 3) ^ (m & 7)) << 3) | (k & 7));
}
// sV[32][128] f16 per buffer (row 256B), 16B-chunk XOR swizzle with row&15.
__device__ __forceinline__ int sV_idx(int n, int j) {
    return n * NN + ((((j >> 3) ^ (n & 15)) << 3) | (j & 7));
}

// One-time: Wt[l][n][k] = W[l][k][n] (f16), WoutT[f][k] = Wout[k][f] (f16).
__global__ void prep_kernel(const float* __restrict__ Ws,
                            const float* __restrict__ Wout,
                            f16* __restrict__ Wt, f16* __restrict__ WoutT) {
    int idx = blockIdx.x * 256 + threadIdx.x;
    if (idx < NL * ND * ND) {
        int l = idx / (ND * ND);
        int r = idx % (ND * ND);
        int n = r >> 8;
        int k = r & 255;
        Wt[idx] = (f16)Ws[l * ND * ND + k * ND + n];
    }
    if (idx < NF * ND) {
        int f = idx >> 8;
        int k = idx & 255;
        WoutT[idx] = (f16)Wout[k * NF + f];
    }
}

__global__ __launch_bounds__(512, 4)
void hgcn_kernel(const float* __restrict__ x,
                 const float* __restrict__ adj,
                 const float* __restrict__ node_mask,
                 const f16*  __restrict__ Wt,
                 const float* __restrict__ bs,
                 const f16*  __restrict__ WoutT,
                 const float* __restrict__ bout,
                 float* __restrict__ out) {
    __shared__ __align__(16) f16 sT[NN * ND];      // [node m][feat k]   64KB
    __shared__ __align__(16) f16 sV[2][32 * NN];   // [n_local][node j]  2x8KB

    const int b    = blockIdx.x;
    const int tid  = threadIdx.x;
    const int wave = tid >> 6;   // 0..7
    const int lane = tid & 63;
    const int lg   = lane >> 4;  // 0..3
    const int lc   = lane & 15;

    const f32x4 fzero = {0.f, 0.f, 0.f, 0.f};

    // ---------- init: sT = f16(logmap0(proj(x[b]))) (wave-private rows) -----
    {
        const float4* xb = (const float4*)(x + (size_t)b * NN * ND);
        for (int r = 0; r < 16; ++r) {
            int row = wave * 16 + r;
            float4 v = xb[row * 64 + lane];
            float ss = v.x * v.x + v.y * v.y + v.z * v.z + v.w * v.w;
            #pragma unroll
            for (int d = 1; d < 64; d <<= 1) ss += __shfl_xor(ss, d);
            float norm = sqrtf(ss);
            float n1  = fmaxf(norm, EPSV);
            float sc1 = (n1 > MAXN) ? (MAXN / n1) : 1.0f;   // proj
            float hn  = norm * sc1;
            float n2  = fmaxf(hn, EPSV);
            float aa  = fminf(n2, MAXN);
            float s   = sc1 * (atanhf(aa) / n2);            // logmap0
            f16x4 t4;
            t4[0] = (f16)(v.x * s); t4[1] = (f16)(v.y * s);
            t4[2] = (f16)(v.z * s); t4[3] = (f16)(v.w * s);
            *(f16x4*)&sT[sT_idx(row, lane * 4)] = t4;
        }
    }

    // ---------- adj B-fragments: load ONCE, reuse 3 layers x 8 chunks ------
    // GEMM-b is U^T = V^T @ adj^T: B[k=j][col=i] needs adj[i][j] j-contig.
    f16x8 adjf[4];
    {
        const float* adjb = adj + (size_t)b * NN * NN;
        #pragma unroll
        for (int ks = 0; ks < 4; ++ks) {
            const float4* ap = (const float4*)(adjb + (wave * 16 + lc) * NN + ks * 32 + lg * 8);
            float4 alo = ap[0], ahi = ap[1];
            f16x8 a;
            a[0] = (f16)alo.x; a[1] = (f16)alo.y; a[2] = (f16)alo.z; a[3] = (f16)alo.w;
            a[4] = (f16)ahi.x; a[5] = (f16)ahi.y; a[6] = (f16)ahi.z; a[7] = (f16)ahi.w;
            adjf[ks] = a;
        }
    }
    __syncthreads();

    for (int layer = 0; layer < NL; ++layer) {
        const f16*   WtL = Wt + layer * ND * ND;
        const float* bsL = bs + layer * ND;

        f32x4 acc_b[16];
        #pragma unroll
        for (int t = 0; t < 16; ++t) acc_b[t] = fzero;

        // GEMM-a chunk: V[m][n-chunk] = T @ W, m-tile = wave, 2 n-tiles.
        // A-frag from sT (own rows), B-frag from Wt (L2). Epilogue: +bias,
        // f16x4 write (4 consecutive m) into sV[buf].
        auto gemm_a = [&](int c) {
            f32x4 acc[2] = {fzero, fzero};
            #pragma unroll
            for (int ks = 0; ks < 8; ++ks) {
                f16x8 afr = *(const f16x8*)&sT[sT_idx(wave * 16 + lc, ks * 32 + lg * 8)];
                #pragma unroll
                for (int ntl = 0; ntl < 2; ++ntl) {
                    int n = c * 32 + ntl * 16 + lc;
                    f16x8 bfr = *(const f16x8*)(WtL + n * ND + ks * 32 + lg * 8);
                    acc[ntl] = __builtin_amdgcn_mfma_f32_16x16x32_f16(afr, bfr, acc[ntl], 0, 0, 0);
                }
            }
            #pragma unroll
            for (int ntl = 0; ntl < 2; ++ntl) {
                int n = c * 32 + ntl * 16 + lc;
                float bias = bsL[n];
                f16x4 v;
                #pragma unroll
                for (int r = 0; r < 4; ++r) v[r] = (f16)(acc[ntl][r] + bias);
                *(f16x4*)&sV[c & 1][sV_idx(ntl * 16 + lc, wave * 16 + lg * 4)] = v;
            }
        };

        // GEMM-b chunk: U^T[n-chunk][i] += V^T[n-chunk][j] * adj[i][j].
        // A-frag from sV[buf], B-frag = adjf (registers).
        auto gemm_b = [&](int c) {
            #pragma unroll
            for (int ks = 0; ks < 4; ++ks) {
                #pragma unroll
                for (int ntl = 0; ntl < 2; ++ntl) {
                    f16x8 afr = *(const f16x8*)&sV[c & 1][sV_idx(ntl * 16 + lc, ks * 32 + lg * 8)];
                    acc_b[c * 2 + ntl] = __builtin_amdgcn_mfma_f32_16x16x32_f16(afr, adjf[ks], acc_b[c * 2 + ntl], 0, 0, 0);
                }
            }
        };

        gemm_a(0);
        #pragma unroll
        for (int c = 0; c < 8; ++c) {
            __syncthreads();
            if (c < 7) gemm_a(c + 1);   // loads overlap gemm_b's MFMAs
            gemm_b(c);
        }

        // epilogue-b: relu, per-node norm (reduce over lg lanes), fused
        // logmap0(proj(expmap0(u))) = u*min(1, ATHMAX/||u||); write own sT rows.
        float ss = 0.f;
        #pragma unroll
        for (int t = 0; t < 16; ++t)
            #pragma unroll
            for (int r = 0; r < 4; ++r) {
                float v = fmaxf(acc_b[t][r], 0.0f);
                acc_b[t][r] = v;
                ss += v * v;
            }
        ss += __shfl_xor(ss, 16);
        ss += __shfl_xor(ss, 32);
        float nu = sqrtf(ss);
        float scale = (nu > ATHMAX) ? (ATHMAX / nu) : 1.0f;
        #pragma unroll
        for (int t = 0; t < 16; ++t) {
            int n0 = (t >> 1) * 32 + (t & 1) * 16 + lg * 4;
            f16x4 v;
            #pragma unroll
            for (int r = 0; r < 4; ++r) v[r] = (f16)(acc_b[t][r] * scale);
            *(f16x4*)&sT[sT_idx(wave * 16 + lc, n0)] = v;
        }
        // no barrier: sT rows are wave-private; sV hazards covered by the
        // barrier at the top of the next chunk loop.
    }

    // ---------- head: out = (out_tan @ Wout + bout) * node_mask ------------
    {
        f32x4 acc = fzero;
        #pragma unroll
        for (int ks = 0; ks < 8; ++ks) {
            f16x8 afr = *(const f16x8*)&sT[sT_idx(wave * 16 + lc, ks * 32 + lg * 8)];
            f16x8 bfr = *(const f16x8*)(WoutT + lc * ND + ks * 32 + lg * 8);
            acc = __builtin_amdgcn_mfma_f32_16x16x32_f16(afr, bfr, acc, 0, 0, 0);
        }
        #pragma unroll
        for (int r = 0; r < 4; ++r) {
            int row = wave * 16 + lg * 4 + r;
            float mask = node_mask[b * NN + row];
            out[((size_t)b * NN + row) * NF + lc] = (acc[r] + bout[lc]) * mask;
        }
    }
}

extern "C" void kernel_launch(void* const* d_in, const int* in_sizes, int n_in,
                              void* d_out, int out_size, void* d_ws, size_t ws_size,
                              hipStream_t stream) {
    const float* x    = (const float*)d_in[0];
    const float* adj  = (const float*)d_in[1];
    const float* mask = (const float*)d_in[2];
    const float* Ws   = (const float*)d_in[3];
    const float* bsp  = (const float*)d_in[4];
    const float* Wout = (const float*)d_in[5];
    const float* bout = (const float*)d_in[6];

    f16* Wt    = (f16*)d_ws;                       // 3*256*256 f16 = 384KB
    f16* WoutT = Wt + NL * ND * ND;                // 16*256 f16 = 8KB

    prep_kernel<<<768, 256, 0, stream>>>(Ws, Wout, Wt, WoutT);
    hgcn_kernel<<<NB, 512, 0, stream>>>(x, adj, mask, Wt, bsp, WoutT, bout,
                                        (float*)d_out);
}

// Round 3
// 88.227 us; speedup vs baseline: 2.5795x; 2.5795x over previous
//
#include <hip/hip_runtime.h>
#include <hip/hip_bf16.h>
#include <math.h>

// HGCN decoder, B=512, N=128, D=256, F=16, L=3, c=1 Poincare ball.
// One 1024-thread block per batch (16 waves -> 4 waves/SIMD at 1 block/CU).
// sT (tangent features, f16) and sV (V^T, f16) both resident in LDS (129KB).
// FP16 MFMA 16x16x32, f32 accumulate. All LDS epilogue writes are f16x4.
// adj MFMA B-fragments converted to f16 registers ONCE, reused for 3 layers.

typedef _Float16 f16;
typedef f16 f16x8 __attribute__((ext_vector_type(8)));
typedef f16 f16x4 __attribute__((ext_vector_type(4)));
typedef float f32x4 __attribute__((ext_vector_type(4)));

#define NB 512
#define NN 128
#define ND 256
#define NF 16
#define NL 3

#define EPSV   1e-7f
#define MAXN   0.99999f      // 1 - 1e-5
#define ATHMAX 6.1030340f    // atanh(1 - 1e-5)

// sT[128][256] f16 (row 512B, 32 16B-chunks), chunk XOR row&7.
__device__ __forceinline__ int sT_idx(int m, int k) {
    return m * ND + ((((k >> 3) ^ (m & 7)) << 3) | (k & 7));
}
// sV[256][128] f16 (row 256B, 16 16B-chunks), chunk XOR row&15.
__device__ __forceinline__ int sV_idx(int n, int j) {
    return n * NN + ((((j >> 3) ^ (n & 15)) << 3) | (j & 7));
}

// One-time: Wt[l][n][k] = W[l][k][n] (f16), WoutT[f][k] = Wout[k][f] (f16).
__global__ void prep_kernel(const float* __restrict__ Ws,
                            const float* __restrict__ Wout,
                            f16* __restrict__ Wt, f16* __restrict__ WoutT) {
    int idx = blockIdx.x * 256 + threadIdx.x;
    if (idx < NL * ND * ND) {
        int l = idx / (ND * ND);
        int r = idx % (ND * ND);
        int n = r >> 8;
        int k = r & 255;
        Wt[idx] = (f16)Ws[l * ND * ND + k * ND + n];
    }
    if (idx < NF * ND) {
        int f = idx >> 8;
        int k = idx & 255;
        WoutT[idx] = (f16)Wout[k * NF + f];
    }
}

__global__ __launch_bounds__(1024, 4)
void hgcn_kernel(const float* __restrict__ x,
                 const float* __restrict__ adj,
                 const float* __restrict__ node_mask,
                 const f16*  __restrict__ Wt,
                 const float* __restrict__ bs,
                 const f16*  __restrict__ WoutT,
                 const float* __restrict__ bout,
                 float* __restrict__ out) {
    __shared__ __align__(16) f16 sT[NN * ND];    // [node m][feat k]  64KB
    __shared__ __align__(16) f16 sV[ND * NN];    // [feat n][node m]  64KB
    __shared__ float sRed[16 * 16];              // wave-pair norm exchange 1KB

    const int b    = blockIdx.x;
    const int tid  = threadIdx.x;
    const int wave = tid >> 6;   // 0..15
    const int lane = tid & 63;
    const int lg   = lane >> 4;  // 0..3
    const int lc   = lane & 15;

    const f32x4 fzero = {0.f, 0.f, 0.f, 0.f};

    // ---------- init: sT = f16(logmap0(proj(x[b]))), 8 rows per wave -------
    {
        const float4* xb = (const float4*)(x + (size_t)b * NN * ND);
        #pragma unroll
        for (int r = 0; r < 8; ++r) {
            int row = wave * 8 + r;
            float4 v = xb[row * 64 + lane];
            float ssq = v.x * v.x + v.y * v.y + v.z * v.z + v.w * v.w;
            #pragma unroll
            for (int d = 1; d < 64; d <<= 1) ssq += __shfl_xor(ssq, d);
            float norm = sqrtf(ssq);
            float n1  = fmaxf(norm, EPSV);
            float sc1 = (n1 > MAXN) ? (MAXN / n1) : 1.0f;   // proj
            float hn  = norm * sc1;
            float n2  = fmaxf(hn, EPSV);
            float aa  = fminf(n2, MAXN);
            float s   = sc1 * (atanhf(aa) / n2);            // logmap0
            f16x4 t4;
            t4[0] = (f16)(v.x * s); t4[1] = (f16)(v.y * s);
            t4[2] = (f16)(v.z * s); t4[3] = (f16)(v.w * s);
            *(f16x4*)&sT[sT_idx(row, lane * 4)] = t4;
        }
    }

    // ---------- adj B-fragments (registers, reused all layers) -------------
    // GEMM-b: U^T[n][i] = sum_j V^T[n][j] * adj[i][j]; B[k=j][col=i], i-tile
    // = wave>>1 (wave pairs share an i-tile and split the n-range).
    f16x8 adjf[4];
    {
        const float* adjb = adj + (size_t)b * NN * NN;
        #pragma unroll
        for (int ks = 0; ks < 4; ++ks) {
            const float4* ap = (const float4*)(adjb + ((wave >> 1) * 16 + lc) * NN + ks * 32 + lg * 8);
            float4 alo = ap[0], ahi = ap[1];
            f16x8 a;
            a[0] = (f16)alo.x; a[1] = (f16)alo.y; a[2] = (f16)alo.z; a[3] = (f16)alo.w;
            a[4] = (f16)ahi.x; a[5] = (f16)ahi.y; a[6] = (f16)ahi.z; a[7] = (f16)ahi.w;
            adjf[ks] = a;
        }
    }
    __syncthreads();

    for (int layer = 0; layer < NL; ++layer) {
        const f16* WtL  = Wt + layer * ND * ND;
        const float bias = bs[layer * ND + wave * 16 + lc];  // n = wave*16+lc

        // ---- GEMM-a: V[m][n] = T @ W + b. Wave owns n-tile = wave, all 8
        // m-tiles. A = sT row m (LDS), B = Wt row n (global/L2, col frag).
        // D: rows m = lg*4+reg (consecutive), col n = lc -> f16x4 sV writes.
        f32x4 acc_a[8];
        #pragma unroll
        for (int t = 0; t < 8; ++t) acc_a[t] = fzero;

        #pragma unroll
        for (int ks = 0; ks < 8; ++ks) {
            f16x8 bfr = *(const f16x8*)(WtL + (wave * 16 + lc) * ND + ks * 32 + lg * 8);
            #pragma unroll
            for (int mt = 0; mt < 8; ++mt) {
                f16x8 afr = *(const f16x8*)&sT[sT_idx(mt * 16 + lc, ks * 32 + lg * 8)];
                acc_a[mt] = __builtin_amdgcn_mfma_f32_16x16x32_f16(afr, bfr, acc_a[mt], 0, 0, 0);
            }
        }
        #pragma unroll
        for (int mt = 0; mt < 8; ++mt) {
            f16x4 v;
            #pragma unroll
            for (int r = 0; r < 4; ++r) v[r] = (f16)(acc_a[mt][r] + bias);
            *(f16x4*)&sV[sV_idx(wave * 16 + lc, mt * 16 + lg * 4)] = v;
        }
        __syncthreads();

        // ---- GEMM-b: U^T[n][i]. i-tile = wave>>1, n-tiles (wave&1)*8+nt.
        // A = sV row n (LDS), B = adjf (registers).
        f32x4 acc_b[8];
        #pragma unroll
        for (int t = 0; t < 8; ++t) acc_b[t] = fzero;

        #pragma unroll
        for (int ks = 0; ks < 4; ++ks) {
            #pragma unroll
            for (int nt = 0; nt < 8; ++nt) {
                f16x8 afr = *(const f16x8*)&sV[sV_idx(((wave & 1) * 8 + nt) * 16 + lc, ks * 32 + lg * 8)];
                acc_b[nt] = __builtin_amdgcn_mfma_f32_16x16x32_f16(afr, adjf[ks], acc_b[nt], 0, 0, 0);
            }
        }

        // ---- epilogue-b: relu, per-node norm over n (this wave has half the
        // n-range; partner wave^1 has the other half -> LDS exchange), fused
        // logmap0(proj(expmap0(u))) = u * min(1, ATHMAX/||u||), write sT.
        float ssq = 0.f;
        #pragma unroll
        for (int t = 0; t < 8; ++t)
            #pragma unroll
            for (int r = 0; r < 4; ++r) {
                float v = fmaxf(acc_b[t][r], 0.0f);
                acc_b[t][r] = v;
                ssq += v * v;
            }
        ssq += __shfl_xor(ssq, 16);   // reduce over lg lanes
        ssq += __shfl_xor(ssq, 32);
        if (lg == 0) sRed[wave * 16 + lc] = ssq;
        __syncthreads();
        float tot = ssq + sRed[(wave ^ 1) * 16 + lc];
        float nu = sqrtf(tot);
        float scale = (nu > ATHMAX) ? (ATHMAX / nu) : 1.0f;

        #pragma unroll
        for (int nt = 0; nt < 8; ++nt) {
            f16x4 v;
            #pragma unroll
            for (int r = 0; r < 4; ++r) v[r] = (f16)(acc_b[nt][r] * scale);
            *(f16x4*)&sT[sT_idx((wave >> 1) * 16 + lc, ((wave & 1) * 8 + nt) * 16 + lg * 4)] = v;
        }
        __syncthreads();
    }

    // ---------- head: out = (out_tan @ Wout + bout) * node_mask ------------
    if (wave < 8) {
        f32x4 acc = fzero;
        #pragma unroll
        for (int ks = 0; ks < 8; ++ks) {
            f16x8 afr = *(const f16x8*)&sT[sT_idx(wave * 16 + lc, ks * 32 + lg * 8)];
            f16x8 bfr = *(const f16x8*)(WoutT + lc * ND + ks * 32 + lg * 8);
            acc = __builtin_amdgcn_mfma_f32_16x16x32_f16(afr, bfr, acc, 0, 0, 0);
        }
        #pragma unroll
        for (int r = 0; r < 4; ++r) {
            int row = wave * 16 + lg * 4 + r;
            float mask = node_mask[b * NN + row];
            out[((size_t)b * NN + row) * NF + lc] = (acc[r] + bout[lc]) * mask;
        }
    }
}

extern "C" void kernel_launch(void* const* d_in, const int* in_sizes, int n_in,
                              void* d_out, int out_size, void* d_ws, size_t ws_size,
                              hipStream_t stream) {
    const float* x    = (const float*)d_in[0];
    const float* adj  = (const float*)d_in[1];
    const float* mask = (const float*)d_in[2];
    const float* Ws   = (const float*)d_in[3];
    const float* bsp  = (const float*)d_in[4];
    const float* Wout = (const float*)d_in[5];
    const float* bout = (const float*)d_in[6];

    f16* Wt    = (f16*)d_ws;                       // 3*256*256 f16 = 384KB
    f16* WoutT = Wt + NL * ND * ND;                // 16*256 f16 = 8KB

    prep_kernel<<<768, 256, 0, stream>>>(Ws, Wout, Wt, WoutT);
    hgcn_kernel<<<NB, 1024, 0, stream>>>(x, adj, mask, Wt, bsp, WoutT, bout,
                                         (float*)d_out);
}